// Round 12
// baseline (355.520 us; speedup 1.0000x reference)
//
#include <hip/hip_runtime.h>
#include <hip/hip_bf16.h>

#define BN_EPS 1e-5f
#define BCAP 16384   // per-bucket edge capacity (mean 8192 + 90 sigma for this graph)

typedef unsigned short u16;
typedef unsigned int u32;
typedef __attribute__((ext_vector_type(8))) short bf16x8v;
typedef __attribute__((ext_vector_type(4))) float f32x4v;

__device__ __forceinline__ float bf2f(u16 u){
    union { u32 i; float f; } c; c.i = ((u32)u) << 16; return c.f;
}
__device__ __forceinline__ u16 f2bf(float f){
    union { float f; u32 i; } c; c.f = f;
    u32 x = c.i;
    u32 r = x + 0x7FFFu + ((x >> 16) & 1u);
    return (u16)(r >> 16);
}
__device__ __forceinline__ float lo16(u32 u){
    union { u32 i; float f; } c; c.i = u << 16; return c.f;
}
__device__ __forceinline__ float hi16(u32 u){
    union { u32 i; float f; } c; c.i = u & 0xFFFF0000u; return c.f;
}
__device__ __forceinline__ u32 pack2(float f0, float f1){
    return (u32)f2bf(f0) | ((u32)f2bf(f1) << 16);
}

// ---------------- dtype detection: one wave ----------------
__global__ void detect_k(const int* __restrict__ ei, const u16* __restrict__ xu,
                         int* __restrict__ flags){
    int lane = threadIdx.x;  // 64
    unsigned long long bal = __ballot(ei[2 * lane + 1] != 0);
    int cnt = 0;
    #pragma unroll
    for (int k = 0; k < 4; ++k){
        u16 u = xu[2 * (lane + 64 * k)];
        int e = (u >> 7) & 0xFF;
        cnt += (e >= 0x70 && e <= 0x86) ? 1 : 0;
    }
    #pragma unroll
    for (int off = 1; off < 64; off <<= 1) cnt += __shfl_xor(cnt, off);
    if (lane == 0){
        flags[0] = (bal == 0ULL) ? 1 : 0;
        flags[1] = (cnt >= 128) ? 1 : 0;
    }
}

// ---------------- fused prep: x->bf16, weights->wT, params->fp32 ----------------
__global__ void prep_k(const void* __restrict__ x, const void* __restrict__ Wl,
                       const void* __restrict__ Wr, const void* __restrict__ b,
                       const void* __restrict__ g, const void* __restrict__ be,
                       u16* __restrict__ xb, u16* __restrict__ wT, float* __restrict__ p,
                       float* __restrict__ ss0, int total4, int wtot, int per,
                       const int* __restrict__ flags){
    int i = blockIdx.x * blockDim.x + threadIdx.x;
    int bf = flags[1];
    if (i < total4){
        if (bf){
            ((uint2*)xb)[i] = ((const uint2*)x)[i];
        } else {
            float4 v = ((const float4*)x)[i];
            ushort4 o; o.x = f2bf(v.x); o.y = f2bf(v.y); o.z = f2bf(v.z); o.w = f2bf(v.w);
            ((ushort4*)xb)[i] = o;
        }
    }
    if (i < wtot){
        u16 vl = bf ? ((const u16*)Wl)[i] : f2bf(((const float*)Wl)[i]);
        u16 vr = bf ? ((const u16*)Wr)[i] : f2bf(((const float*)Wr)[i]);
        int l = i >> 14, r = (i >> 7) & 127, c = i & 127;
        wT[(size_t)(l * 2 + 0) * 16384 + c * 128 + r] = vl;
        wT[(size_t)(l * 2 + 1) * 16384 + c * 128 + r] = vr;
    }
    if (i < per){
        if (i < 128){ ss0[i] = 1.f; ss0[128 + i] = 0.f; }
        if (bf){
            p[i]           = bf2f(((const u16*)b)[i]);
            p[per + i]     = bf2f(((const u16*)g)[i]);
            p[2 * per + i] = bf2f(((const u16*)be)[i]);
        } else {
            p[i]           = ((const float*)b)[i];
            p[per + i]     = ((const float*)g)[i];
            p[2 * per + i] = ((const float*)be)[i];
        }
    }
}

// ---------------- CSR build: two-level bucket sort, zero global atomics ----------
__global__ __launch_bounds__(1024) void phist_k(const void* __restrict__ ei, int E,
                                                int tile, u32* __restrict__ blockHist,
                                                const int* __restrict__ flags){
    __shared__ u32 lh[128];
    int tid = threadIdx.x;
    if (tid < 128) lh[tid] = 0u;
    __syncthreads();
    int start = blockIdx.x * tile;
    int end = min(E, start + tile);
    int i64 = flags[0];
    for (int i = start + tid; i < end; i += 1024){
        int d = i64 ? (int)((const long long*)ei)[E + i] : ((const int*)ei)[E + i];
        atomicAdd(&lh[d >> 9], 1u);
    }
    __syncthreads();
    if (tid < 128) blockHist[blockIdx.x * 128 + tid] = lh[tid];
}

__global__ void bases_k(const u32* __restrict__ blockHist, u32* __restrict__ blockBase,
                        int* __restrict__ rangeBase, int* __restrict__ rowptrN, int nb){
    __shared__ u32 t_s[128];
    int k = threadIdx.x;  // 128
    u32 run = 0;
    for (int b = 0; b < nb; ++b){
        blockBase[b * 128 + k] = run;
        run += blockHist[b * 128 + k];
    }
    t_s[k] = min(run, (u32)BCAP);
    __syncthreads();
    if (k == 0){
        u32 r = 0;
        for (int j = 0; j < 128; ++j){ u32 v = t_s[j]; t_s[j] = r; r += v; }
        rangeBase[128] = (int)r;
        *rowptrN = (int)r;
    }
    __syncthreads();
    rangeBase[k] = (int)t_s[k];
}

__global__ __launch_bounds__(1024) void pscat_k(const void* __restrict__ ei, int E,
                                                int tile, const u32* __restrict__ blockBase,
                                                u32* __restrict__ part,
                                                const int* __restrict__ flags){
    __shared__ u32 lcur[128];
    int tid = threadIdx.x;
    if (tid < 128) lcur[tid] = blockBase[blockIdx.x * 128 + tid];
    __syncthreads();
    int start = blockIdx.x * tile;
    int end = min(E, start + tile);
    int i64 = flags[0];
    for (int i = start + tid; i < end; i += 1024){
        int s, d;
        if (i64){
            const long long* p = (const long long*)ei;
            s = (int)p[i]; d = (int)p[E + i];
        } else {
            const int* p = (const int*)ei;
            s = p[i]; d = p[E + i];
        }
        int k = d >> 9;
        u32 pos = atomicAdd(&lcur[k], 1u);
        if (pos < BCAP) part[(size_t)k * BCAP + pos] = (u32)(u16)s | ((u32)(d & 511) << 16);
    }
}

__global__ __launch_bounds__(1024) void build_k(const u32* __restrict__ part,
                                                const int* __restrict__ rangeBase,
                                                int* __restrict__ rowptr,
                                                float* __restrict__ dinv,
                                                u16* __restrict__ col, int N){
    __shared__ u32 bins[512];
    __shared__ u32 wsum[8];
    __shared__ u16 sorted[BCAP];   // 32 KB
    int k   = blockIdx.x;
    int tid = threadIdx.x;
    int base = rangeBase[k];
    int cntk = rangeBase[k + 1] - base;
    int d0   = k << 9;
    if (tid < 512) bins[tid] = 0u;
    __syncthreads();
    const u32* pk = part + (size_t)k * BCAP;
    for (int i = tid; i < cntk; i += 1024)
        atomicAdd(&bins[pk[i] >> 16], 1u);
    __syncthreads();
    int lane = tid & 63, w = tid >> 6;
    u32 v = (tid < 512) ? bins[tid] : 0u;
    u32 sc = v;
    #pragma unroll
    for (int off = 1; off < 64; off <<= 1){
        u32 u = __shfl_up(sc, off);
        if (lane >= off) sc += u;
    }
    if (lane == 63 && w < 8) wsum[w] = sc;
    __syncthreads();
    if (tid == 0){
        u32 r = 0;
        #pragma unroll
        for (int j = 0; j < 8; ++j){ u32 t = wsum[j]; wsum[j] = r; r += t; }
    }
    __syncthreads();
    u32 excl = (w < 8 ? wsum[w] : 0u) + sc - v;
    if (tid < 512){
        int d = d0 + tid;
        if (d < N){
            rowptr[d] = base + (int)excl;
            dinv[d] = 1.f / fmaxf((float)v, 1.f);
        }
        bins[tid] = excl;
    }
    __syncthreads();
    for (int i = tid; i < cntk; i += 1024){
        u32 e = pk[i];
        u32 pos = atomicAdd(&bins[e >> 16], 1u);
        sorted[pos] = (u16)e;
    }
    __syncthreads();
    for (int i = tid; i < cntk; i += 1024)
        col[base + i] = sorted[i];
}

// -------- fused layer: gather(mean, fused BN+ReLU) -> LDS tile -> dual-GEMM + stats ----
// 512 thr = 8 waves; 32 nodes/block. Gather: wave w -> nodes m0+4w..+3.
// GEMM: wave w -> rows (w&1)*16, cols (w>>1)*32 (2 MFMA tiles).
__global__ __launch_bounds__(512) void layer_k(
        const u16* __restrict__ state, const float* __restrict__ ssT, int relu,
        const int* __restrict__ rowptr, const u16* __restrict__ col,
        const float* __restrict__ dinv, const u16* __restrict__ wT,
        const float* __restrict__ bias, u16* __restrict__ hp16,
        float* __restrict__ stats, int N){
    __shared__ u16 aT[32][136];    // +8 pad: 16B-aligned rows, 2-way bank aliasing (free)
    __shared__ float s_ss[256];
    __shared__ float s_stat[256];
    int tid  = threadIdx.x;
    int lane = tid & 63;
    int w    = tid >> 6;          // 0..7
    int m0   = blockIdx.x * 32;
    if (tid < 256){ s_ss[tid] = ssT[tid]; s_stat[tid] = 0.f; }
    __syncthreads();

    // ---------- phase 1: gather 4 nodes per wave ----------
    {
        int q   = lane >> 4;
        int sub = lane & 15;
        float sc[8], sh[8];
        #pragma unroll
        for (int j = 0; j < 8; ++j){
            sc[j] = s_ss[sub * 8 + j];
            sh[j] = s_ss[128 + sub * 8 + j];
        }
        #pragma unroll
        for (int nn = 0; nn < 4; ++nn){
            int lrow = w * 4 + nn;
            int node = m0 + lrow;
            if (node < N){
                int s = rowptr[node], e = rowptr[node + 1];
                float a[8] = {0.f,0.f,0.f,0.f,0.f,0.f,0.f,0.f};
                int i = s + q;
                for (; i + 4 < e; i += 8){
                    int sn0 = col[i], sn1 = col[i + 4];
                    uint4 v0 = *(const uint4*)(state + (size_t)sn0 * 128 + sub * 8);
                    uint4 v1 = *(const uint4*)(state + (size_t)sn1 * 128 + sub * 8);
                    float f0[8], f1[8];
                    f0[0]=lo16(v0.x); f0[1]=hi16(v0.x); f0[2]=lo16(v0.y); f0[3]=hi16(v0.y);
                    f0[4]=lo16(v0.z); f0[5]=hi16(v0.z); f0[6]=lo16(v0.w); f0[7]=hi16(v0.w);
                    f1[0]=lo16(v1.x); f1[1]=hi16(v1.x); f1[2]=lo16(v1.y); f1[3]=hi16(v1.y);
                    f1[4]=lo16(v1.z); f1[5]=hi16(v1.z); f1[6]=lo16(v1.w); f1[7]=hi16(v1.w);
                    #pragma unroll
                    for (int j = 0; j < 8; ++j){
                        float t0 = f0[j] * sc[j] + sh[j];
                        float t1 = f1[j] * sc[j] + sh[j];
                        if (relu){ t0 = fmaxf(t0, 0.f); t1 = fmaxf(t1, 0.f); }
                        a[j] += t0 + t1;
                    }
                }
                if (i < e){
                    int sn = col[i];
                    uint4 v = *(const uint4*)(state + (size_t)sn * 128 + sub * 8);
                    float f[8];
                    f[0]=lo16(v.x); f[1]=hi16(v.x); f[2]=lo16(v.y); f[3]=hi16(v.y);
                    f[4]=lo16(v.z); f[5]=hi16(v.z); f[6]=lo16(v.w); f[7]=hi16(v.w);
                    #pragma unroll
                    for (int j = 0; j < 8; ++j){
                        float t = f[j] * sc[j] + sh[j];
                        if (relu) t = fmaxf(t, 0.f);
                        a[j] += t;
                    }
                }
                #pragma unroll
                for (int off = 16; off < 64; off <<= 1){
                    #pragma unroll
                    for (int j = 0; j < 8; ++j) a[j] += __shfl_xor(a[j], off);
                }
                if (q == 0){
                    float di = dinv[node];
                    uint4 o;
                    o.x = pack2(a[0] * di, a[1] * di);
                    o.y = pack2(a[2] * di, a[3] * di);
                    o.z = pack2(a[4] * di, a[5] * di);
                    o.w = pack2(a[6] * di, a[7] * di);
                    *(uint4*)(&aT[lrow][sub * 8]) = o;
                }
            } else if (q == 0){
                uint4 z = {0u,0u,0u,0u};
                *(uint4*)(&aT[lrow][sub * 8]) = z;
            }
        }
    }
    __syncthreads();

    // ---------- phase 2: dual GEMM ----------
    int hl   = lane & 15;
    int quad = lane >> 4;
    int rh   = w & 1;            // row-half: 16 rows
    int cq   = w >> 1;           // col-quarter: 32 cols (2 tiles)
    int rowg = m0 + rh * 16 + hl;
    int ar   = min(rowg, N - 1);
    const u16* srow = state + (size_t)ar * 128 + quad * 8;
    const u16* Bp0  = wT + (size_t)(cq * 32 + hl) * 128 + quad * 8;

    f32x4v acc[2];
    acc[0] = (f32x4v){0.f,0.f,0.f,0.f};
    acc[1] = (f32x4v){0.f,0.f,0.f,0.f};

    #pragma unroll
    for (int kc = 0; kc < 128; kc += 32){
        // A-mean from LDS
        bf16x8v am = *(const bf16x8v*)(&aT[rh * 16 + hl][quad * 8 + kc]);
        // A-state from global, fused BN(+ReLU)
        int kb = quad * 8 + kc;
        uint4 raw = *(const uint4*)(srow + kc);
        float f[8];
        f[0]=lo16(raw.x); f[1]=hi16(raw.x); f[2]=lo16(raw.y); f[3]=hi16(raw.y);
        f[4]=lo16(raw.z); f[5]=hi16(raw.z); f[6]=lo16(raw.w); f[7]=hi16(raw.w);
        float t8[8];
        #pragma unroll
        for (int j = 0; j < 8; ++j){
            float t = f[j] * s_ss[kb + j] + s_ss[128 + kb + j];
            if (relu) t = fmaxf(t, 0.f);
            t8[j] = t;
        }
        union { bf16x8v v; u32 u[4]; } fr;
        fr.u[0] = pack2(t8[0], t8[1]);
        fr.u[1] = pack2(t8[2], t8[3]);
        fr.u[2] = pack2(t8[4], t8[5]);
        fr.u[3] = pack2(t8[6], t8[7]);
        bf16x8v as = fr.v;
        #pragma unroll
        for (int t = 0; t < 2; ++t){
            bf16x8v b0 = *(const bf16x8v*)(Bp0 + t * 2048 + kc);
            bf16x8v b1 = *(const bf16x8v*)(Bp0 + 16384 + t * 2048 + kc);
            acc[t] = __builtin_amdgcn_mfma_f32_16x16x32_bf16(am, b0, acc[t], 0, 0, 0);
            acc[t] = __builtin_amdgcn_mfma_f32_16x16x32_bf16(as, b1, acc[t], 0, 0, 0);
        }
    }

    bool valid = (m0 + rh * 16 < N);   // N multiple of 16: whole 16-row tile valid or not
    #pragma unroll
    for (int t = 0; t < 2; ++t){
        int c = cq * 32 + t * 16 + hl;
        float bv = bias[c];
        float cs = 0.f, cqs = 0.f;
        if (valid){
            #pragma unroll
            for (int r = 0; r < 4; ++r){
                float v = acc[t][r] + bv;
                hp16[(size_t)(m0 + rh * 16 + quad * 4 + r) * 128 + c] = f2bf(v);
                cs += v; cqs += v * v;
            }
        }
        cs  += __shfl_xor(cs, 16);  cs  += __shfl_xor(cs, 32);
        cqs += __shfl_xor(cqs, 16); cqs += __shfl_xor(cqs, 32);
        if (quad == 0 && valid){
            atomicAdd(&s_stat[c], cs);
            atomicAdd(&s_stat[128 + c], cqs);
        }
    }
    __syncthreads();
    if (tid < 256){
        float* st = stats + (size_t)(blockIdx.x & 63) * 256;
        atomicAdd(&st[tid], s_stat[tid]);
    }
}

// reduce buckets -> scale/shift; re-zero stats for next layer
__global__ void finalize_k(float* __restrict__ stats, const float* __restrict__ g,
                           const float* __restrict__ be, float* __restrict__ ss, float invN){
    int j = threadIdx.x;  // 128
    float s = 0.f, sq = 0.f;
    #pragma unroll 8
    for (int bkt = 0; bkt < 64; ++bkt){
        s  += stats[bkt * 256 + j];
        sq += stats[bkt * 256 + 128 + j];
        stats[bkt * 256 + j] = 0.f;
        stats[bkt * 256 + 128 + j] = 0.f;
    }
    float mu  = s * invN;
    float var = sq * invN - mu * mu;
    if (!(mu == mu)) mu = 0.f;
    if (!(var >= 0.f) || !(var == var)) var = 0.f;
    float sc = g[j] * rsqrtf(var + BN_EPS);
    ss[j]       = sc;
    ss[128 + j] = be[j] - mu * sc;
}

// final BN+ReLU: bf16 pre-BN in, fp32 out
__global__ void applyf_k(const u16* __restrict__ in, const float* __restrict__ ss,
                         float* __restrict__ out, int total4){
    int i = blockIdx.x * blockDim.x + threadIdx.x;
    if (i >= total4) return;
    uint2 u = ((const uint2*)in)[i];
    float4 v;
    v.x = lo16(u.x); v.y = hi16(u.x); v.z = lo16(u.y); v.w = hi16(u.y);
    if (!(v.x == v.x)) v.x = 0.f;
    if (!(v.y == v.y)) v.y = 0.f;
    if (!(v.z == v.z)) v.z = 0.f;
    if (!(v.w == v.w)) v.w = 0.f;
    int c = (i & 31) * 4;
    float4 o;
    o.x = fmaxf(v.x * ss[c]     + ss[128 + c], 0.f);
    o.y = fmaxf(v.y * ss[c + 1] + ss[129 + c], 0.f);
    o.z = fmaxf(v.z * ss[c + 2] + ss[130 + c], 0.f);
    o.w = fmaxf(v.w * ss[c + 3] + ss[131 + c], 0.f);
    ((float4*)out)[i] = o;
}

extern "C" void kernel_launch(void* const* d_in, const int* in_sizes, int n_in,
                              void* d_out, int out_size, void* d_ws, size_t ws_size,
                              hipStream_t stream){
    const void* x  = d_in[0];
    const int*  ei = (const int*)d_in[1];
    const void* Wl = d_in[2];
    const void* Wr = d_in[3];
    const void* b  = d_in[4];
    const void* gm = d_in[5];
    const void* bt = d_in[6];
    float* outf = (float*)d_out;

    const int N = in_sizes[0] / 128;   // u16 keys/col assume N < 65536 (N=50000 here)
    const int E = in_sizes[1] / 2;
    const int L = in_sizes[2] / 16384;
    const int PB = 128;
    const int TILE = (E + PB - 1) / PB;

    char* wsp = (char*)d_ws;
    size_t off = 0;
    auto alloc = [&](size_t bytes) -> char* {
        char* p = wsp + off;
        off = (off + bytes + 255) & ~(size_t)255;
        return p;
    };
    int*   flags  = (int*)  alloc(16);
    int*   rowptr = (int*)  alloc((size_t)(N + 1) * 4);
    u16*   col    = (u16*)  alloc((size_t)E * 2);
    float* dinv   = (float*)alloc((size_t)N * 4);
    u32*   bHist  = (u32*)  alloc((size_t)PB * 128 * 4);
    u32*   bBase  = (u32*)  alloc((size_t)PB * 128 * 4);
    int*   rangeB = (int*)  alloc((size_t)129 * 4);
    u32*   part   = (u32*)  alloc((size_t)128 * BCAP * 4);
    u16*   wT     = (u16*)  alloc((size_t)L * 2 * 16384 * 2);
    float* pvec   = (float*)alloc((size_t)3 * L * 128 * 4);
    float* ssb    = (float*)alloc((size_t)(L + 1) * 256 * 4);
    u16*   xb     = (u16*)  alloc((size_t)N * 128 * 2);
    float* stats  = (float*)alloc((size_t)64 * 256 * 4);
    u16*   hpre16 = (u16*)  alloc((size_t)N * 128 * 2);
    u16*   hA     = (u16*)  alloc((size_t)N * 128 * 2);
    u16*   hB     = (u16*)  alloc((size_t)N * 128 * 2);
    (void)ws_size; (void)n_in; (void)out_size;

    detect_k<<<1, 64, 0, stream>>>(ei, (const u16*)x, flags);
    hipMemsetAsync(stats, 0, (size_t)64 * 256 * 4, stream);

    // CSR build: two-level bucket sort, zero global atomics, coalesced writes
    phist_k<<<PB, 1024, 0, stream>>>((const void*)ei, E, TILE, bHist, flags);
    bases_k<<<1, 128, 0, stream>>>(bHist, bBase, rangeB, rowptr + N, PB);
    pscat_k<<<PB, 1024, 0, stream>>>((const void*)ei, E, TILE, bBase, part, flags);
    build_k<<<128, 1024, 0, stream>>>(part, rangeB, rowptr, dinv, col, N);

    prep_k<<<(N * 32 + 255) / 256, 256, 0, stream>>>(x, Wl, Wr, b, gm, bt, xb, wT, pvec,
                                                     ssb, N * 32, L * 16384, L * 128, flags);

    // carried state is PRE-BN bf16; layer_k fuses BN+ReLU on both A-paths
    const u16* state = xb;
    int gblocks = (N + 31) / 32;
    for (int l = 0; l < L; ++l){
        int last = (l == L - 1);
        int relu = (l > 0);
        const float* ssT = ssb + (size_t)l * 256;
        u16* nxt = last ? hpre16 : ((l & 1) ? hB : hA);
        layer_k<<<gblocks, 512, 0, stream>>>(state, ssT, relu, rowptr, col, dinv,
                                             wT + (size_t)l * 2 * 16384, pvec + l * 128,
                                             nxt, stats, N);
        finalize_k<<<1, 128, 0, stream>>>(stats, pvec + (size_t)L * 128 + l * 128,
                                          pvec + (size_t)2 * L * 128 + l * 128,
                                          ssb + (size_t)(l + 1) * 256, 1.f / (float)N);
        state = nxt;
    }
    applyf_k<<<(N * 32 + 255) / 256, 256, 0, stream>>>(hpre16, ssb + (size_t)L * 256,
                                                       outf, N * 32);
}

// Round 13
// 350.615 us; speedup vs baseline: 1.0140x; 1.0140x over previous
//
#include <hip/hip_runtime.h>
#include <hip/hip_bf16.h>

#define BN_EPS 1e-5f
#define BCAP 16384   // per-bucket edge capacity (mean 8192 + 90 sigma for this graph)

typedef unsigned short u16;
typedef unsigned int u32;
typedef __attribute__((ext_vector_type(8))) short bf16x8v;
typedef __attribute__((ext_vector_type(4))) float f32x4v;

__device__ __forceinline__ float bf2f(u16 u){
    union { u32 i; float f; } c; c.i = ((u32)u) << 16; return c.f;
}
__device__ __forceinline__ u16 f2bf(float f){
    union { float f; u32 i; } c; c.f = f;
    u32 x = c.i;
    u32 r = x + 0x7FFFu + ((x >> 16) & 1u);
    return (u16)(r >> 16);
}
__device__ __forceinline__ float lo16(u32 u){
    union { u32 i; float f; } c; c.i = u << 16; return c.f;
}
__device__ __forceinline__ float hi16(u32 u){
    union { u32 i; float f; } c; c.i = u & 0xFFFF0000u; return c.f;
}
__device__ __forceinline__ u32 pack2(float f0, float f1){
    return (u32)f2bf(f0) | ((u32)f2bf(f1) << 16);
}

// ---------------- dtype detection: one wave ----------------
__global__ void detect_k(const int* __restrict__ ei, const u16* __restrict__ xu,
                         int* __restrict__ flags){
    int lane = threadIdx.x;  // 64
    unsigned long long bal = __ballot(ei[2 * lane + 1] != 0);
    int cnt = 0;
    #pragma unroll
    for (int k = 0; k < 4; ++k){
        u16 u = xu[2 * (lane + 64 * k)];
        int e = (u >> 7) & 0xFF;
        cnt += (e >= 0x70 && e <= 0x86) ? 1 : 0;
    }
    #pragma unroll
    for (int off = 1; off < 64; off <<= 1) cnt += __shfl_xor(cnt, off);
    if (lane == 0){
        flags[0] = (bal == 0ULL) ? 1 : 0;
        flags[1] = (cnt >= 128) ? 1 : 0;
    }
}

// ---------------- fused prep: x->bf16, weights->wT, params->fp32 ----------------
__global__ void prep_k(const void* __restrict__ x, const void* __restrict__ Wl,
                       const void* __restrict__ Wr, const void* __restrict__ b,
                       const void* __restrict__ g, const void* __restrict__ be,
                       u16* __restrict__ xb, u16* __restrict__ wT, float* __restrict__ p,
                       int total4, int wtot, int per, const int* __restrict__ flags){
    int i = blockIdx.x * blockDim.x + threadIdx.x;
    int bf = flags[1];
    if (i < total4){
        if (bf){
            ((uint2*)xb)[i] = ((const uint2*)x)[i];
        } else {
            float4 v = ((const float4*)x)[i];
            ushort4 o; o.x = f2bf(v.x); o.y = f2bf(v.y); o.z = f2bf(v.z); o.w = f2bf(v.w);
            ((ushort4*)xb)[i] = o;
        }
    }
    if (i < wtot){
        u16 vl = bf ? ((const u16*)Wl)[i] : f2bf(((const float*)Wl)[i]);
        u16 vr = bf ? ((const u16*)Wr)[i] : f2bf(((const float*)Wr)[i]);
        int l = i >> 14, r = (i >> 7) & 127, c = i & 127;
        wT[(size_t)(l * 2 + 0) * 16384 + c * 128 + r] = vl;
        wT[(size_t)(l * 2 + 1) * 16384 + c * 128 + r] = vr;
    }
    if (i < per){
        if (bf){
            p[i]           = bf2f(((const u16*)b)[i]);
            p[per + i]     = bf2f(((const u16*)g)[i]);
            p[2 * per + i] = bf2f(((const u16*)be)[i]);
        } else {
            p[i]           = ((const float*)b)[i];
            p[per + i]     = ((const float*)g)[i];
            p[2 * per + i] = ((const float*)be)[i];
        }
    }
}

// ---------------- CSR build: two-level bucket sort, zero global atomics ----------
__global__ __launch_bounds__(1024) void phist_k(const void* __restrict__ ei, int E,
                                                int tile, u32* __restrict__ blockHist,
                                                const int* __restrict__ flags){
    __shared__ u32 lh[128];
    int tid = threadIdx.x;
    if (tid < 128) lh[tid] = 0u;
    __syncthreads();
    int start = blockIdx.x * tile;
    int end = min(E, start + tile);
    int i64 = flags[0];
    for (int i = start + tid; i < end; i += 1024){
        int d = i64 ? (int)((const long long*)ei)[E + i] : ((const int*)ei)[E + i];
        atomicAdd(&lh[d >> 9], 1u);
    }
    __syncthreads();
    if (tid < 128) blockHist[blockIdx.x * 128 + tid] = lh[tid];
}

__global__ void bases_k(const u32* __restrict__ blockHist, u32* __restrict__ blockBase,
                        int* __restrict__ rangeBase, int* __restrict__ rowptrN, int nb){
    __shared__ u32 t_s[128];
    int k = threadIdx.x;  // 128
    u32 run = 0;
    for (int b = 0; b < nb; ++b){
        blockBase[b * 128 + k] = run;
        run += blockHist[b * 128 + k];
    }
    t_s[k] = min(run, (u32)BCAP);
    __syncthreads();
    if (k == 0){
        u32 r = 0;
        for (int j = 0; j < 128; ++j){ u32 v = t_s[j]; t_s[j] = r; r += v; }
        rangeBase[128] = (int)r;
        *rowptrN = (int)r;
    }
    __syncthreads();
    rangeBase[k] = (int)t_s[k];
}

__global__ __launch_bounds__(1024) void pscat_k(const void* __restrict__ ei, int E,
                                                int tile, const u32* __restrict__ blockBase,
                                                u32* __restrict__ part,
                                                const int* __restrict__ flags){
    __shared__ u32 lcur[128];
    int tid = threadIdx.x;
    if (tid < 128) lcur[tid] = blockBase[blockIdx.x * 128 + tid];
    __syncthreads();
    int start = blockIdx.x * tile;
    int end = min(E, start + tile);
    int i64 = flags[0];
    for (int i = start + tid; i < end; i += 1024){
        int s, d;
        if (i64){
            const long long* p = (const long long*)ei;
            s = (int)p[i]; d = (int)p[E + i];
        } else {
            const int* p = (const int*)ei;
            s = p[i]; d = p[E + i];
        }
        int k = d >> 9;
        u32 pos = atomicAdd(&lcur[k], 1u);
        if (pos < BCAP) part[(size_t)k * BCAP + pos] = (u32)(u16)s | ((u32)(d & 511) << 16);
    }
}

__global__ __launch_bounds__(1024) void build_k(const u32* __restrict__ part,
                                                const int* __restrict__ rangeBase,
                                                int* __restrict__ rowptr,
                                                float* __restrict__ dinv,
                                                u16* __restrict__ col, int N){
    __shared__ u32 bins[512];
    __shared__ u32 wsum[8];
    __shared__ u16 sorted[BCAP];   // 32 KB
    int k   = blockIdx.x;
    int tid = threadIdx.x;
    int base = rangeBase[k];
    int cntk = rangeBase[k + 1] - base;
    int d0   = k << 9;
    if (tid < 512) bins[tid] = 0u;
    __syncthreads();
    const u32* pk = part + (size_t)k * BCAP;
    for (int i = tid; i < cntk; i += 1024)
        atomicAdd(&bins[pk[i] >> 16], 1u);
    __syncthreads();
    int lane = tid & 63, w = tid >> 6;
    u32 v = (tid < 512) ? bins[tid] : 0u;
    u32 sc = v;
    #pragma unroll
    for (int off = 1; off < 64; off <<= 1){
        u32 u = __shfl_up(sc, off);
        if (lane >= off) sc += u;
    }
    if (lane == 63 && w < 8) wsum[w] = sc;
    __syncthreads();
    if (tid == 0){
        u32 r = 0;
        #pragma unroll
        for (int j = 0; j < 8; ++j){ u32 t = wsum[j]; wsum[j] = r; r += t; }
    }
    __syncthreads();
    u32 excl = (w < 8 ? wsum[w] : 0u) + sc - v;
    if (tid < 512){
        int d = d0 + tid;
        if (d < N){
            rowptr[d] = base + (int)excl;
            dinv[d] = 1.f / fmaxf((float)v, 1.f);
        }
        bins[tid] = excl;
    }
    __syncthreads();
    for (int i = tid; i < cntk; i += 1024){
        u32 e = pk[i];
        u32 pos = atomicAdd(&bins[e >> 16], 1u);
        sorted[pos] = (u16)e;
    }
    __syncthreads();
    for (int i = tid; i < cntk; i += 1024)
        col[base + i] = sorted[i];
}

// ---------------- mean aggregation (clean post-BN input), 8 edges in flight ----------
__global__ void agg_k(const u16* __restrict__ h, const int* __restrict__ rowptr,
                      const u16* __restrict__ col, const float* __restrict__ dinv,
                      u16* __restrict__ meanb, int N){
    int wid  = (blockIdx.x * blockDim.x + threadIdx.x) >> 6;
    int lane = threadIdx.x & 63;
    if (wid >= N) return;
    int q   = lane >> 4;
    int sub = lane & 15;
    int s = rowptr[wid], e = rowptr[wid + 1];
    float a[8] = {0.f,0.f,0.f,0.f,0.f,0.f,0.f,0.f};
    int i = s + q;
    for (; i + 4 < e; i += 8){
        int sn0 = col[i], sn1 = col[i + 4];
        uint4 v0 = *(const uint4*)(h + (size_t)sn0 * 128 + sub * 8);
        uint4 v1 = *(const uint4*)(h + (size_t)sn1 * 128 + sub * 8);
        a[0] += lo16(v0.x) + lo16(v1.x); a[1] += hi16(v0.x) + hi16(v1.x);
        a[2] += lo16(v0.y) + lo16(v1.y); a[3] += hi16(v0.y) + hi16(v1.y);
        a[4] += lo16(v0.z) + lo16(v1.z); a[5] += hi16(v0.z) + hi16(v1.z);
        a[6] += lo16(v0.w) + lo16(v1.w); a[7] += hi16(v0.w) + hi16(v1.w);
    }
    if (i < e){
        int sn = col[i];
        uint4 v = *(const uint4*)(h + (size_t)sn * 128 + sub * 8);
        a[0] += lo16(v.x); a[1] += hi16(v.x);
        a[2] += lo16(v.y); a[3] += hi16(v.y);
        a[4] += lo16(v.z); a[5] += hi16(v.z);
        a[6] += lo16(v.w); a[7] += hi16(v.w);
    }
    #pragma unroll
    for (int off = 16; off < 64; off <<= 1){
        #pragma unroll
        for (int j = 0; j < 8; ++j) a[j] += __shfl_xor(a[j], off);
    }
    if (q == 0){
        float di = dinv[wid];
        uint4 o;
        o.x = pack2(a[0] * di, a[1] * di);
        o.y = pack2(a[2] * di, a[3] * di);
        o.z = pack2(a[4] * di, a[5] * di);
        o.w = pack2(a[6] * di, a[7] * di);
        *(uint4*)(meanb + (size_t)wid * 128 + sub * 8) = o;
    }
}

// ---------------- dual-GEMM + bias + BN-stats; 32 rows/wave; raw bf16 A-loads ---------
__global__ __launch_bounds__(256) void gemm_k(
        const u16* __restrict__ Aa, const u16* __restrict__ Ab,
        const u16* __restrict__ wT, const float* __restrict__ bias,
        u16* __restrict__ hp16, float* __restrict__ stats, int N){
    __shared__ float s_stat[256];
    int tid  = threadIdx.x;
    int lane = tid & 63;
    int w    = tid >> 6;
    int wid  = blockIdx.x * 4 + w;
    int hl   = lane & 15;
    int quad = lane >> 4;
    int m0   = wid * 32;
    s_stat[tid] = 0.f;
    __syncthreads();

    f32x4v acc[2][8];
    #pragma unroll
    for (int r2 = 0; r2 < 2; ++r2)
        #pragma unroll
        for (int t = 0; t < 8; ++t) acc[r2][t] = (f32x4v){0.f, 0.f, 0.f, 0.f};

    if (m0 < N){
        const u16* arow0[2];
        const u16* arow1[2];
        #pragma unroll
        for (int r2 = 0; r2 < 2; ++r2){
            int rb = m0 + r2 * 16;
            if (rb + 16 > N) rb = N - 16;   // clamp; stores/stats for invalid tile skipped
            arow0[r2] = Aa + (size_t)(rb + hl) * 128 + quad * 8;
            arow1[r2] = Ab + (size_t)(rb + hl) * 128 + quad * 8;
        }
        #pragma unroll
        for (int half = 0; half < 2; ++half){
            const u16* A0 = half ? arow1[0] : arow0[0];
            const u16* A1 = half ? arow1[1] : arow0[1];
            const u16* Bp = wT + half * 16384 + (size_t)hl * 128 + quad * 8;
            #pragma unroll
            for (int kc = 0; kc < 128; kc += 32){
                bf16x8v af0 = *(const bf16x8v*)(A0 + kc);
                bf16x8v af1 = *(const bf16x8v*)(A1 + kc);
                #pragma unroll
                for (int t = 0; t < 8; ++t){
                    bf16x8v bf = *(const bf16x8v*)(Bp + t * 2048 + kc);
                    acc[0][t] = __builtin_amdgcn_mfma_f32_16x16x32_bf16(af0, bf, acc[0][t], 0, 0, 0);
                    acc[1][t] = __builtin_amdgcn_mfma_f32_16x16x32_bf16(af1, bf, acc[1][t], 0, 0, 0);
                }
            }
        }
    }

    #pragma unroll
    for (int r2 = 0; r2 < 2; ++r2){
        int mb = m0 + r2 * 16;
        bool valid = (mb < N);
        #pragma unroll
        for (int t = 0; t < 8; ++t){
            int c = t * 16 + hl;
            float bv = bias[c];
            float cs = 0.f, cq = 0.f;
            if (valid){
                #pragma unroll
                for (int r = 0; r < 4; ++r){
                    float v = acc[r2][t][r] + bv;
                    hp16[(size_t)(mb + quad * 4 + r) * 128 + c] = f2bf(v);
                    cs += v; cq += v * v;
                }
            }
            cs += __shfl_xor(cs, 16); cs += __shfl_xor(cs, 32);
            cq += __shfl_xor(cq, 16); cq += __shfl_xor(cq, 32);
            if (quad == 0 && valid){
                atomicAdd(&s_stat[c], cs);
                atomicAdd(&s_stat[128 + c], cq);
            }
        }
    }
    __syncthreads();
    float* st = stats + (size_t)(blockIdx.x & 63) * 256;
    atomicAdd(&st[tid], s_stat[tid]);
}

// reduce buckets -> scale/shift; re-zero stats for next layer
__global__ void finalize_k(float* __restrict__ stats, const float* __restrict__ g,
                           const float* __restrict__ be, float* __restrict__ ss, float invN){
    int j = threadIdx.x;  // 128
    float s = 0.f, sq = 0.f;
    #pragma unroll 8
    for (int bkt = 0; bkt < 64; ++bkt){
        s  += stats[bkt * 256 + j];
        sq += stats[bkt * 256 + 128 + j];
        stats[bkt * 256 + j] = 0.f;
        stats[bkt * 256 + 128 + j] = 0.f;
    }
    float mu  = s * invN;
    float var = sq * invN - mu * mu;
    if (!(mu == mu)) mu = 0.f;
    if (!(var >= 0.f) || !(var == var)) var = 0.f;
    float sc = g[j] * rsqrtf(var + BN_EPS);
    ss[j]       = sc;
    ss[128 + j] = be[j] - mu * sc;
}

// BN+ReLU: bf16 pre-BN in; bf16 post-BN out (mid layers) or fp32 out (final)
__global__ void apply_k(const u16* __restrict__ in, const float* __restrict__ ss,
                        u16* __restrict__ outb, float* __restrict__ outf, int use_f32,
                        int total4){
    int i = blockIdx.x * blockDim.x + threadIdx.x;
    if (i >= total4) return;
    uint2 u = ((const uint2*)in)[i];
    float4 v;
    v.x = lo16(u.x); v.y = hi16(u.x); v.z = lo16(u.y); v.w = hi16(u.y);
    if (!(v.x == v.x)) v.x = 0.f;
    if (!(v.y == v.y)) v.y = 0.f;
    if (!(v.z == v.z)) v.z = 0.f;
    if (!(v.w == v.w)) v.w = 0.f;
    int c = (i & 31) * 4;
    float r0 = fmaxf(v.x * ss[c]     + ss[128 + c], 0.f);
    float r1 = fmaxf(v.y * ss[c + 1] + ss[129 + c], 0.f);
    float r2 = fmaxf(v.z * ss[c + 2] + ss[130 + c], 0.f);
    float r3 = fmaxf(v.w * ss[c + 3] + ss[131 + c], 0.f);
    if (use_f32){
        float4 o; o.x = r0; o.y = r1; o.z = r2; o.w = r3;
        ((float4*)outf)[i] = o;
    } else {
        uint2 o; o.x = pack2(r0, r1); o.y = pack2(r2, r3);
        ((uint2*)outb)[i] = o;
    }
}

extern "C" void kernel_launch(void* const* d_in, const int* in_sizes, int n_in,
                              void* d_out, int out_size, void* d_ws, size_t ws_size,
                              hipStream_t stream){
    const void* x  = d_in[0];
    const int*  ei = (const int*)d_in[1];
    const void* Wl = d_in[2];
    const void* Wr = d_in[3];
    const void* b  = d_in[4];
    const void* gm = d_in[5];
    const void* bt = d_in[6];
    float* outf = (float*)d_out;

    const int N = in_sizes[0] / 128;   // u16 keys/col assume N < 65536 (N=50000 here)
    const int E = in_sizes[1] / 2;
    const int L = in_sizes[2] / 16384;
    const int PB = 128;
    const int TILE = (E + PB - 1) / PB;

    char* wsp = (char*)d_ws;
    size_t off = 0;
    auto alloc = [&](size_t bytes) -> char* {
        char* p = wsp + off;
        off = (off + bytes + 255) & ~(size_t)255;
        return p;
    };
    int*   flags  = (int*)  alloc(16);
    int*   rowptr = (int*)  alloc((size_t)(N + 1) * 4);
    u16*   col    = (u16*)  alloc((size_t)E * 2);
    float* dinv   = (float*)alloc((size_t)N * 4);
    u32*   bHist  = (u32*)  alloc((size_t)PB * 128 * 4);
    u32*   bBase  = (u32*)  alloc((size_t)PB * 128 * 4);
    int*   rangeB = (int*)  alloc((size_t)129 * 4);
    u32*   part   = (u32*)  alloc((size_t)128 * BCAP * 4);
    u16*   wT     = (u16*)  alloc((size_t)L * 2 * 16384 * 2);
    float* pvec   = (float*)alloc((size_t)3 * L * 128 * 4);
    float* ss     = (float*)alloc(256 * 4);
    u16*   xb     = (u16*)  alloc((size_t)N * 128 * 2);
    u16*   meanb  = (u16*)  alloc((size_t)N * 128 * 2);
    float* stats  = (float*)alloc((size_t)64 * 256 * 4);
    u16*   hpre16 = (u16*)  alloc((size_t)N * 128 * 2);
    u16*   hA     = (u16*)  alloc((size_t)N * 128 * 2);
    u16*   hB     = (u16*)  alloc((size_t)N * 128 * 2);
    (void)ws_size; (void)n_in; (void)out_size;

    detect_k<<<1, 64, 0, stream>>>(ei, (const u16*)x, flags);
    hipMemsetAsync(stats, 0, (size_t)64 * 256 * 4, stream);

    // CSR build: two-level bucket sort, zero global atomics, coalesced writes
    phist_k<<<PB, 1024, 0, stream>>>((const void*)ei, E, TILE, bHist, flags);
    bases_k<<<1, 128, 0, stream>>>(bHist, bBase, rangeB, rowptr + N, PB);
    pscat_k<<<PB, 1024, 0, stream>>>((const void*)ei, E, TILE, bBase, part, flags);
    build_k<<<128, 1024, 0, stream>>>(part, rangeB, rowptr, dinv, col, N);

    prep_k<<<(N * 32 + 255) / 256, 256, 0, stream>>>(x, Wl, Wr, b, gm, bt, xb, wT, pvec,
                                                     N * 32, L * 16384, L * 128, flags);

    // carried state is POST-BN bf16 (x itself for layer 0); no transform in hot kernels
    const u16* state = xb;
    int nwaves = (N + 31) / 32;
    int gblocks = (nwaves + 3) / 4;
    for (int l = 0; l < L; ++l){
        int last = (l == L - 1);
        u16* nxt = (l & 1) ? hB : hA;
        agg_k<<<(N + 3) / 4, 256, 0, stream>>>(state, rowptr, col, dinv, meanb, N);
        gemm_k<<<gblocks, 256, 0, stream>>>(meanb, state, wT + (size_t)l * 2 * 16384,
                                            pvec + l * 128, hpre16, stats, N);
        finalize_k<<<1, 128, 0, stream>>>(stats, pvec + (size_t)L * 128 + l * 128,
                                          pvec + (size_t)2 * L * 128 + l * 128,
                                          ss, 1.f / (float)N);
        apply_k<<<(N * 32 + 255) / 256, 256, 0, stream>>>(hpre16, ss, nxt, outf, last,
                                                          N * 32);
        state = nxt;
    }
}